// Round 6
// baseline (134.564 us; speedup 1.0000x reference)
//
#include <hip/hip_runtime.h>
#include <math.h>

#define NROWS 8192
#define DDIM  128
#define K20   28.853900817779268f        // 20 * log2(e)
#define K2    (K20 * K20)                // 832.5476
#define DTHR  8.3255f                    // 0.01 * K2 : diagonal mask (real pairs >= ~750)
#define JSPLIT 8                         // j-segments of 1024 cols
#define NT 32                            // 32-col tiles per segment

typedef _Float16 f16x8 __attribute__((ext_vector_type(8)));
typedef _Float16 f16x4 __attribute__((ext_vector_type(4)));
typedef float    f32x16 __attribute__((ext_vector_type(16)));

// ws layout (floats after xh): sums[0..N) = nL (sum exp(-40d) over non-diag),
//                              sums[N..2N) = nS (sum exp(-20d) over non-diag)

// ---- fp32 -> f16 conversion + zero sums/out ----
__global__ void convert_kernel(const float* __restrict__ x,
                               _Float16* __restrict__ xh,
                               float* __restrict__ sums,
                               float* __restrict__ out) {
    int idx = (blockIdx.x * 256 + threadIdx.x) * 4;
    float4 v = *(const float4*)(x + idx);
    f16x4 h = { (_Float16)v.x, (_Float16)v.y, (_Float16)v.z, (_Float16)v.w };
    *(f16x4*)(xh + idx) = h;
    if (threadIdx.x < 16) sums[blockIdx.x * 16 + threadIdx.x] = 0.0f;  // 1024*16 = 2*NROWS
    if (blockIdx.x == 0 && threadIdx.x == 0) out[0] = 0.0f;
}

// ---- main pair kernel: barrier-free, register double-buffered B prefetch.
//      Wave owns a 32-row strip x 1024-col segment (32 tiles). All pairs as
//      negatives; diagonal excluded by value (d2s < 8.33 iff j==i). Positives
//      fixed up inside finalize_kernel. ----
__global__ __launch_bounds__(256, 2) void pair_kernel(
        const _Float16* __restrict__ xh,
        float* __restrict__ sums) {
    const int w = threadIdx.x >> 6;
    const int lane = threadIdx.x & 63;
    const int i0 = (blockIdx.x * 4 + w) * 32;     // this wave's 32-row strip
    const int jbase = blockIdx.y * (NT * 32);     // block-shared 1024-col segment (L1 reuse)
    const int lrow = lane & 31;
    const int koff = (lane >> 5) * 8;

    // A fragment: lane l supplies A[m=lrow][k = kk*16 + koff + 0..7]
    f16x8 afrag[8];
    #pragma unroll
    for (int kk = 0; kk < 8; ++kk)
        afrag[kk] = *(const f16x8*)(xh + (size_t)(i0 + lrow) * DDIM + kk * 16 + koff);

    float nL[16], nS[16];
    #pragma unroll
    for (int r = 0; r < 16; ++r) { nL[r] = 0.f; nS[r] = 0.f; }

    const _Float16* bbase = xh + (size_t)(jbase + lrow) * DDIM + koff;

    // MFMA chain + epilogue for one 32x32 tile held in b[8]
    auto compute = [&](const f16x8* b) {
        f32x16 acc = {0.f,0.f,0.f,0.f,0.f,0.f,0.f,0.f,0.f,0.f,0.f,0.f,0.f,0.f,0.f,0.f};
        #pragma unroll
        for (int kk = 0; kk < 8; ++kk)
            acc = __builtin_amdgcn_mfma_f32_32x32x16_f16(afrag[kk], b[kk], acc, 0, 0, 0);
        #pragma unroll
        for (int r = 0; r < 16; ++r) {
            float d2s = fmaf(-2.0f * K2, acc[r], 2.0f * K2);     // (20*log2e)^2 * d^2
            float ds  = __builtin_amdgcn_sqrtf(d2s);             // 20*log2e*d (NaN on diag)
            float tt  = __builtin_amdgcn_exp2f(-ds);             // exp(-20 d)
            tt = (d2s < DTHR) ? 0.0f : tt;                       // exact diagonal exclusion
            nS[r] += tt;
            nL[r] = fmaf(tt, tt, nL[r]);                         // exp(-40 d)
        }
    };

    f16x8 bA[8], bB[8];
    #pragma unroll
    for (int kk = 0; kk < 8; ++kk) bA[kk] = *(const f16x8*)(bbase + kk * 16);

    for (int jt = 0; jt < NT; jt += 2) {
        const _Float16* p1 = bbase + (size_t)(jt + 1) * 32 * DDIM;
        #pragma unroll
        for (int kk = 0; kk < 8; ++kk) bB[kk] = *(const f16x8*)(p1 + kk * 16);
        compute(bA);                                   // loads of jt+1 in flight
        const _Float16* p2 = bbase + (size_t)((jt + 2) & (NT - 1)) * 32 * DDIM;
        #pragma unroll
        for (int kk = 0; kk < 8; ++kk) bA[kk] = *(const f16x8*)(p2 + kk * 16);
        compute(bB);                                   // loads of jt+2 in flight
    }

    // reduce across the 32 column-lanes; lanes 0 / 32 hold 16 row-sums each
    #pragma unroll
    for (int r = 0; r < 16; ++r) {
        float a = nL[r], b = nS[r];
        #pragma unroll
        for (int m = 1; m < 32; m <<= 1) {
            a += __shfl_xor(a, m, 64);
            b += __shfl_xor(b, m, 64);
        }
        if ((lane & 31) == 0) {
            const int row = (r & 3) + 8 * (r >> 2) + 4 * (lane >> 5);  // C/D row map (m74/m101)
            atomicAdd(&sums[i0 + row], a);
            atomicAdd(&sums[NROWS + i0 + row], b);
        }
    }
}

// ---- finalize + positive-pair correction. Block owns 256 rows = 32 whole
//      classes; each thread handles one row: recompute its 7 same-class pairs
//      (fp32 dot over the same f16 inputs), add pos sums, subtract the
//      contributions pair_kernel counted as negatives, then the loss. ----
__global__ void finalize_kernel(const _Float16* __restrict__ xh,
                                const float* __restrict__ sums,
                                float* __restrict__ out) {
    const int i = blockIdx.x * 256 + threadIdx.x;
    const int c8 = i & ~7;                 // class base row
    const int ii = i & 7;

    f16x8 xi[16];
    #pragma unroll
    for (int k = 0; k < 16; ++k)
        xi[k] = *(const f16x8*)(xh + (size_t)i * DDIM + k * 8);

    float pL = 0.f, pS = 0.f, subL = 0.f, subS = 0.f;
    #pragma unroll
    for (int jj = 0; jj < 8; ++jj) {
        if (jj == ii) continue;
        const _Float16* pj = xh + (size_t)(c8 + jj) * DDIM;
        float dot = 0.f;
        #pragma unroll
        for (int k = 0; k < 16; ++k) {
            f16x8 b = *(const f16x8*)(pj + k * 8);
            #pragma unroll
            for (int u = 0; u < 8; ++u)
                dot = fmaf((float)xi[k][u], (float)b[u], dot);
        }
        float d2 = fmaf(-2.f, dot, 2.f);
        float d  = sqrtf(fmaxf(d2, 1e-12f));           // reference clamp
        float tt = __builtin_amdgcn_exp2f(-d * K20);   // exp(-20 d)
        pS += __builtin_amdgcn_exp2f(d * K20);         // exp(+20 d)
        pL = fmaf(tt, tt, pL);
        float tp = (d2 * K2 < DTHR) ? 0.f : tt;        // what pair_kernel added
        subS += tp;
        subL = fmaf(tp, tp, subL);
    }

    float nL = sums[i] - subL;
    float nS = sums[NROWS + i] - subS;
    float aLr  = 1.0f - pL / (pL + nL);
    float posL = logf(pS) - 16.0f;    // log(sum exp(20(d-0.8)))
    float negL = logf(nS) + 22.0f;    // log(sum exp(20(1.1-d)))
    float v = aLr * (posL + negL);

    #pragma unroll
    for (int m = 32; m; m >>= 1) v += __shfl_xor(v, m, 64);
    __shared__ float partial[4];
    int wv = threadIdx.x >> 6, lane = threadIdx.x & 63;
    if (lane == 0) partial[wv] = v;
    __syncthreads();
    if (threadIdx.x == 0) {
        float s = partial[0] + partial[1] + partial[2] + partial[3];
        atomicAdd(out, s * (1.0f / NROWS));
    }
}

extern "C" void kernel_launch(void* const* d_in, const int* in_sizes, int n_in,
                              void* d_out, int out_size, void* d_ws, size_t ws_size,
                              hipStream_t stream) {
    const float* x = (const float*)d_in[0];
    float* out = (float*)d_out;

    _Float16* xh = (_Float16*)d_ws;              // 2 MB
    float* sums  = (float*)(xh + NROWS * DDIM);  // 2*NROWS floats

    convert_kernel<<<NROWS * DDIM / (256 * 4), 256, 0, stream>>>(x, xh, sums, out);
    dim3 grid(NROWS / (4 * 32), JSPLIT);         // 64 x 8 = 512 blocks = 2048 waves (2/SIMD)
    pair_kernel<<<grid, 256, 0, stream>>>(xh, sums);
    finalize_kernel<<<NROWS / 256, 256, 0, stream>>>(xh, sums, out);
}